// Round 2
// baseline (2310.783 us; speedup 1.0000x reference)
//
#include <hip/hip_runtime.h>

// Problem constants (B=1024, C=1024, H=W=8 -> HW=64, 16 heads, hd=64)
#define BATCH 1024
#define CH    1024
#define HW    64
#define NHEAD 16
#define HDIM  64
#define PIX   (BATCH*HW)          // 65536
#define KDIM  1024
#define LN_EPS 1e-5f
#define NORM_EPS 1e-12f
#define TEMP_EPS 1e-6f

typedef __bf16 bf16;
typedef __bf16 bf16x8 __attribute__((ext_vector_type(8)));
typedef float  f32x4  __attribute__((ext_vector_type(4)));

// async global->LDS 16B copy: LDS dest is wave-uniform base + lane*16
__device__ __forceinline__ void async_copy16(bf16* lds, const bf16* g) {
    __builtin_amdgcn_global_load_lds((const __attribute__((address_space(1))) void*)g,
                                     (__attribute__((address_space(3))) void*)lds, 16, 0, 0);
}

// ---------------- prep kernels ----------------

__global__ void cvt_f32_bf16(const float* __restrict__ src, bf16* __restrict__ dst, int n) {
    int i = blockIdx.x * 256 + threadIdx.x;
    if (i < n) dst[i] = (bf16)src[i];
}

__global__ void pack_bias(const float* __restrict__ bq, const float* __restrict__ bk,
                          const float* __restrict__ bv, float* __restrict__ dst) {
    int i = blockIdx.x * 256 + threadIdx.x;
    if (i < 1024)      dst[i] = bq[i];
    else if (i < 2048) dst[i] = bk[i - 1024];
    else if (i < 3072) dst[i] = bv[i - 2048];
}

// x[b][c][hw] fp32 -> xT[pix][c] bf16  (pix = b*64+hw), LDS transpose, both sides coalesced
__global__ void transpose_x(const float* __restrict__ x, bf16* __restrict__ xT) {
    __shared__ float tile[32][65];
    int b = blockIdx.y, ct = blockIdx.x, t = threadIdx.x;
    const float* xb = x + (size_t)b * (CH*HW) + (size_t)ct * 32 * HW;
    for (int it = 0; it < 8; ++it) {
        int cl = (t >> 6) + it * 4;
        int hw = t & 63;
        tile[cl][hw] = xb[cl * HW + hw];
    }
    __syncthreads();
    bf16* dst = xT + (size_t)b * HW * KDIM + ct * 32;
    // vectorized stores: each thread packs 4 consecutive c -> 8B store
    for (int it = 0; it < 2; ++it) {
        int hw = (t >> 3) + it * 32;
        int g4 = t & 7;
        bf16 p4[4];
        for (int j = 0; j < 4; ++j) p4[j] = (bf16)tile[4 * g4 + j][hw];
        *(uint2*)&dst[(size_t)hw * KDIM + 4 * g4] = *(uint2*)p4;
    }
}

// ---------------- PERSISTENT GEMM qkv: 256x256 tile, 8-phase counted-vmcnt ----------------
// D[pix][o] = sum_k xT[pix][k] * W[o][k] + bias[o]   out [PIX][3072] bf16
// grid = 256 blocks (1/CU); block b owns pix-tile b (pix0 = b*256) and loops over all
// 12 o-tiles. A base never changes; at it=7 the kt>=16 stages redirect to next o-tile's B.
// Pipeline state after phase 7 == prologue state -> NO drain across tile boundaries.
// Previous tile's accumulators are dumped (and zeroed) quadrant-wise in phases 0-1 of the
// next tile's first iteration, so the C-write overlaps staging. Bias lives in LDS (a global
// load at the dump site would make the compiler emit vmcnt(0) and drain the pipeline).

#define READ_A(buf, qm) \
    { _Pragma("unroll") \
      for (int tm = 0; tm < 4; ++tm) { \
        _Pragma("unroll") \
        for (int ks = 0; ks < 2; ++ks) { \
          const int r_ = (qm)*64 + tm*16 + ln; \
          af[tm][ks] = *(const bf16x8*)&sm[buf][0][wm][r_*64 + (((ks*4 + quad) ^ (ln & 7)) * 8)]; \
        } } }

#define READ_B(buf, tn0, tn1) \
    { _Pragma("unroll") \
      for (int tn = (tn0); tn < (tn1); ++tn) { \
        _Pragma("unroll") \
        for (int ks = 0; ks < 2; ++ks) { \
          const int r_ = (wn & 1)*64 + tn*16 + ln; \
          bb[tn][ks] = *(const bf16x8*)&sm[buf][1][wn >> 1][r_*64 + (((ks*4 + quad) ^ (ln & 7)) * 8)]; \
        } } }

#define MMAQ(qm, qn) \
    { __builtin_amdgcn_s_setprio(1); \
      _Pragma("unroll") \
      for (int tm = 0; tm < 4; ++tm) { \
        _Pragma("unroll") \
        for (int tn2 = 0; tn2 < 2; ++tn2) { \
          const int tn_ = (qn)*2 + tn2; \
          acc[(qm)*4 + tm][tn_] = __builtin_amdgcn_mfma_f32_16x16x32_bf16(af[tm][0], bb[tn_][0], acc[(qm)*4 + tm][tn_], 0, 0, 0); \
          acc[(qm)*4 + tm][tn_] = __builtin_amdgcn_mfma_f32_16x16x32_bf16(af[tm][1], bb[tn_][1], acc[(qm)*4 + tm][tn_], 0, 0, 0); \
        } } \
      __builtin_amdgcn_s_setprio(0); }

// one half-tile = 128 rows x 64 k (16 KB); 512 thr x 2 x 16B. base: gA or gB panel base.
#define STAGE(buf, op, half, base, ktm) \
    { const bf16* g_ = (base) + (size_t)((half)*128) * KDIM + (ktm)*64; \
      bf16* lb_ = &sm[buf][op][half][0]; \
      _Pragma("unroll") \
      for (int l = 0; l < 2; ++l) { \
        const int s_ = (l*8 + w)*64 + lane; \
        const int row_ = s_ >> 3, cc_ = (s_ & 7) ^ (row_ & 7); \
        async_copy16(lb_ + (l*8 + w)*512, g_ + (size_t)row_*KDIM + cc_*8); \
      } }

// dump + zero quadrant (qm,qn) of acc for o-tile base o0p (bias from LDS -> lgkm only)
#define DUMPQ(qm, qn, o0p) \
    { _Pragma("unroll") \
      for (int tm2 = 0; tm2 < 4; ++tm2) { \
        const int tm_ = (qm)*4 + tm2; \
        const int row0_ = pix0 + 128*wm + 16*tm_ + quad*4; \
        _Pragma("unroll") \
        for (int tn2 = 0; tn2 < 2; ++tn2) { \
          const int tn_ = (qn)*2 + tn2; \
          const int col_ = (o0p) + 64*wn + 16*tn_ + ln; \
          const float b_ = bias_lds[col_]; \
          _Pragma("unroll") \
          for (int r = 0; r < 4; ++r) \
            out[(size_t)(row0_ + r) * 3072 + col_] = (bf16)(acc[tm_][tn_][r] + b_); \
          acc[tm_][tn_] = (f32x4){0.f, 0.f, 0.f, 0.f}; \
        } } }

#define BAR()   __builtin_amdgcn_s_barrier()
#define LGKM0() asm volatile("s_waitcnt lgkmcnt(0)" ::: "memory")
#define VM6()   asm volatile("s_waitcnt vmcnt(6)" ::: "memory")

__global__ __launch_bounds__(512, 2) void gemm_qkv(const bf16* __restrict__ Ap,   // xT [PIX][1024]
                                                   const bf16* __restrict__ Wqk,  // [3072][1024]
                                                   const float* __restrict__ bias,
                                                   bf16* __restrict__ out) {      // [PIX][3072]
    __shared__ bf16 sm[2][2][2][128 * 64];   // [dbuf][A/B][half] -> 128 KiB
    __shared__ float bias_lds[3072];
    const int t = threadIdx.x;
    const int pix0 = blockIdx.x * 256;       // block owns this pix-tile for all 12 o-tiles
    const int w = t >> 6, lane = t & 63, quad = lane >> 4, ln = lane & 15;
    const int wm = w >> 2, wn = w & 3;       // 2 x 4 wave grid

    const bf16* gA = Ap + (size_t)pix0 * KDIM;

    f32x4 acc[8][4];
#pragma unroll
    for (int i = 0; i < 8; ++i)
#pragma unroll
        for (int j = 0; j < 4; ++j)
            acc[i][j] = (f32x4){0.f, 0.f, 0.f, 0.f};

    bf16x8 af[4][2], bb[4][2];

    // prologue: bias -> LDS; stage tile0 K-tile0 fully + K-tile1's Bh0,Bh1,Ah0
    for (int j = t; j < 3072; j += 512) bias_lds[j] = bias[j];
    {
        const bf16* gB = Wqk;   // o-tile 0
        STAGE(0, 1, 0, gB, 0);
        STAGE(0, 1, 1, gB, 0);
        STAGE(0, 0, 0, gA, 0);
        STAGE(0, 0, 1, gA, 0);
        STAGE(1, 1, 0, gB, 1);
        STAGE(1, 1, 1, gB, 1);
        STAGE(1, 0, 0, gA, 1);
    }
    LGKM0();            // publish bias_lds writes before barrier
    VM6();              // 14 loads outstanding -> wait 8 oldest = K-tile0 landed
    BAR();

    for (int ot = 0; ot < 12; ++ot) {
        const bf16* gBt = Wqk + (size_t)(ot * 256) * KDIM;
        const bf16* gBn = (ot < 11) ? (gBt + (size_t)256 * KDIM) : gBt;  // clamp: harmless reload
        const int o0p = (ot - 1) * 256;      // o-tile being dumped (ot>0 only)

        // ---- it = 0: dump previous tile's acc in phases 0-1, k0 = 0 ----
        {
            READ_A(0, 0);
            if (wn < 2) { READ_B(0, 0, 4); } else { READ_B(0, 0, 2); }
            STAGE(1, 0, 1, gA, 1);
            if (ot) { DUMPQ(0, 0, o0p); DUMPQ(1, 0, o0p); }
            BAR(); LGKM0(); MMAQ(0, 0); BAR();

            if (wn >= 2) { READ_B(0, 2, 4); }
            STAGE(0, 1, 0, gBt, 2);
            if (ot) { DUMPQ(0, 1, o0p); DUMPQ(1, 1, o0p); }
            BAR(); LGKM0(); MMAQ(0, 1); BAR();

            READ_A(0, 1);
            STAGE(0, 1, 1, gBt, 2);
            BAR(); LGKM0(); MMAQ(1, 1); BAR();

            STAGE(0, 0, 0, gA, 2);
            VM6();
            BAR(); LGKM0(); MMAQ(1, 0); BAR();

            READ_A(1, 0);
            if (wn < 2) { READ_B(1, 0, 4); } else { READ_B(1, 0, 2); }
            STAGE(0, 0, 1, gA, 2);
            BAR(); LGKM0(); MMAQ(0, 0); BAR();

            if (wn >= 2) { READ_B(1, 2, 4); }
            STAGE(1, 1, 0, gBt, 3);
            BAR(); LGKM0(); MMAQ(0, 1); BAR();

            READ_A(1, 1);
            STAGE(1, 1, 1, gBt, 3);
            BAR(); LGKM0(); MMAQ(1, 1); BAR();

            STAGE(1, 0, 0, gA, 3);
            VM6();
            BAR(); LGKM0(); MMAQ(1, 0); BAR();
        }

        // ---- it = 1..6: steady state ----
        for (int it = 1; it < 7; ++it) {
            const int k0 = 2 * it;
            READ_A(0, 0);
            if (wn < 2) { READ_B(0, 0, 4); } else { READ_B(0, 0, 2); }
            STAGE(1, 0, 1, gA, k0 + 1);
            BAR(); LGKM0(); MMAQ(0, 0); BAR();

            if (wn >= 2) { READ_B(0, 2, 4); }
            STAGE(0, 1, 0, gBt, k0 + 2);
            BAR(); LGKM0(); MMAQ(0, 1); BAR();

            READ_A(0, 1);
            STAGE(0, 1, 1, gBt, k0 + 2);
            BAR(); LGKM0(); MMAQ(1, 1); BAR();

            STAGE(0, 0, 0, gA, k0 + 2);
            VM6();
            BAR(); LGKM0(); MMAQ(1, 0); BAR();

            READ_A(1, 0);
            if (wn < 2) { READ_B(1, 0, 4); } else { READ_B(1, 0, 2); }
            STAGE(0, 0, 1, gA, k0 + 2);
            BAR(); LGKM0(); MMAQ(0, 0); BAR();

            if (wn >= 2) { READ_B(1, 2, 4); }
            STAGE(1, 1, 0, gBt, k0 + 3);
            BAR(); LGKM0(); MMAQ(0, 1); BAR();

            READ_A(1, 1);
            STAGE(1, 1, 1, gBt, k0 + 3);
            BAR(); LGKM0(); MMAQ(1, 1); BAR();

            STAGE(1, 0, 0, gA, k0 + 3);
            VM6();
            BAR(); LGKM0(); MMAQ(1, 0); BAR();
        }

        // ---- it = 7: kt 16/17 stages wrap to next o-tile's B (A base unchanged) ----
        {
            READ_A(0, 0);
            if (wn < 2) { READ_B(0, 0, 4); } else { READ_B(0, 0, 2); }
            STAGE(1, 0, 1, gA, 15);
            BAR(); LGKM0(); MMAQ(0, 0); BAR();

            if (wn >= 2) { READ_B(0, 2, 4); }
            STAGE(0, 1, 0, gBn, 0);
            BAR(); LGKM0(); MMAQ(0, 1); BAR();

            READ_A(0, 1);
            STAGE(0, 1, 1, gBn, 0);
            BAR(); LGKM0(); MMAQ(1, 1); BAR();

            STAGE(0, 0, 0, gA, 0);
            VM6();
            BAR(); LGKM0(); MMAQ(1, 0); BAR();

            READ_A(1, 0);
            if (wn < 2) { READ_B(1, 0, 4); } else { READ_B(1, 0, 2); }
            STAGE(0, 0, 1, gA, 0);
            BAR(); LGKM0(); MMAQ(0, 0); BAR();

            if (wn >= 2) { READ_B(1, 2, 4); }
            STAGE(1, 1, 0, gBn, 1);
            BAR(); LGKM0(); MMAQ(0, 1); BAR();

            READ_A(1, 1);
            STAGE(1, 1, 1, gBn, 1);
            BAR(); LGKM0(); MMAQ(1, 1); BAR();

            STAGE(1, 0, 0, gA, 1);
            VM6();
            BAR(); LGKM0(); MMAQ(1, 0); BAR();
        }
    }

    asm volatile("s_waitcnt vmcnt(0)" ::: "memory");   // drain tail stages
    // final dump: last o-tile (o0 = 2816)
    DUMPQ(0, 0, 2816);
    DUMPQ(0, 1, 2816);
    DUMPQ(1, 0, 2816);
    DUMPQ(1, 1, 2816);
}

// ---------------- attention per (b, h) ----------------
// qkv layout: [pix][3072]  (q: cols h*64+d, k: 1024+h*64+d, v: 2048+h*64+d)
// normalize q,k over spatial dim n; attn = softmax((q.k)/(T+eps)); out[n][d] -> attnout[pix][c]

__global__ __launch_bounds__(256) void attn_kernel(const bf16* __restrict__ qkv,
                                                   bf16* __restrict__ attnout,
                                                   const float* __restrict__ temp) {
    __shared__ bf16 qs[64][72];
    __shared__ bf16 ksld[64][72];
    __shared__ bf16 vs[64][72];   // transposed: vs[d][m]
    __shared__ bf16 ps[64][72];   // softmax probs [n][m]
    __shared__ float rsq[64], rsk[64];

    int h = blockIdx.x, b = blockIdx.y, t = threadIdx.x;
    int w = t >> 6, lane = t & 63, quad = lane >> 4, ln = lane & 15;
    const bf16* base = qkv + (size_t)b * HW * 3072 + h * HDIM;

    // stage q, k: rows = spatial n, cols = d (contiguous)
    for (int it = 0; it < 2; ++it) {
        int row = (t >> 3) + it * 32, ch = t & 7;
        *(uint4*)&qs[row][ch * 8]   = *(const uint4*)&base[(size_t)row * 3072 + ch * 8];
        *(uint4*)&ksld[row][ch * 8] = *(const uint4*)&base[(size_t)row * 3072 + 1024 + ch * 8];
    }
    // stage v transposed -> vs[d][m]
    for (int it = 0; it < 2; ++it) {
        int m = t & 63, dg = (t >> 6) * 8 + it * 32;
        uint4 v4 = *(const uint4*)&base[(size_t)m * 3072 + 2048 + dg];
        bf16 tmpv[8];
        *(uint4*)tmpv = v4;
        for (int j = 0; j < 8; ++j) vs[dg + j][m] = tmpv[j];
    }
    __syncthreads();

    // l2 norms over n for each d: all 256 threads (each sums 32 rows, pair-combine)
    {
        int d = (t >> 1) & 63, seg = t & 1;
        float ssum = 0.f;
        if (t < 128) {
            for (int n = seg * 32; n < seg * 32 + 32; ++n) { float v = (float)qs[n][d]; ssum += v * v; }
        } else {
            for (int n = seg * 32; n < seg * 32 + 32; ++n) { float v = (float)ksld[n][d]; ssum += v * v; }
        }
        ssum += __shfl_xor(ssum, 1);
        if (seg == 0) {
            float r = 1.0f / fmaxf(sqrtf(ssum), NORM_EPS);
            if (t < 128) rsq[d] = r; else rsk[d] = r;
        }
    }
    __syncthreads();
    for (int it = 0; it < 16; ++it) {
        int e = t + 256 * it;
        int n = e >> 6, d = e & 63;
        qs[n][d]   = (bf16)((float)qs[n][d] * rsq[d]);
        ksld[n][d] = (bf16)((float)ksld[n][d] * rsk[d]);
    }
    __syncthreads();

    // QK^T: attn[n][m] = sum_d q[d][n] k[d][m];  wave w -> rows n in [16w,16w+16)
    f32x4 acc[4];
    for (int i = 0; i < 4; ++i) acc[i] = (f32x4){0.f, 0.f, 0.f, 0.f};
    bf16x8 aq[2];
    for (int ks = 0; ks < 2; ++ks)
        aq[ks] = *(const bf16x8*)&qs[16 * w + ln][ks * 32 + quad * 8];
    for (int tn = 0; tn < 4; ++tn)
        for (int ks = 0; ks < 2; ++ks) {
            bf16x8 bk = *(const bf16x8*)&ksld[16 * tn + ln][ks * 32 + quad * 8];
            acc[tn] = __builtin_amdgcn_mfma_f32_16x16x32_bf16(aq[ks], bk, acc[tn], 0, 0, 0);
        }

    float invt = 1.0f / (temp[0] + TEMP_EPS);
    for (int r = 0; r < 4; ++r) {
        float v[4];
        for (int tn = 0; tn < 4; ++tn) v[tn] = acc[tn][r] * invt;
        float mx = fmaxf(fmaxf(v[0], v[1]), fmaxf(v[2], v[3]));
        for (int mask = 1; mask < 16; mask <<= 1) mx = fmaxf(mx, __shfl_xor(mx, mask));
        float p[4], s = 0.f;
        for (int tn = 0; tn < 4; ++tn) { p[tn] = __expf(v[tn] - mx); s += p[tn]; }
        for (int mask = 1; mask < 16; mask <<= 1) s += __shfl_xor(s, mask);
        float inv = 1.0f / s;
        int n = 16 * w + quad * 4 + r;
        for (int tn = 0; tn < 4; ++tn)
            ps[n][16 * tn + ln] = (bf16)(p[tn] * inv);
    }
    __syncthreads();

    // PV: out[n][d] = sum_m attn[n][m] v[d][m]
    f32x4 acc2[4];
    for (int i = 0; i < 4; ++i) acc2[i] = (f32x4){0.f, 0.f, 0.f, 0.f};
    bf16x8 ap[2];
    for (int ks = 0; ks < 2; ++ks)
        ap[ks] = *(const bf16x8*)&ps[16 * w + ln][ks * 32 + quad * 8];
    for (int tn = 0; tn < 4; ++tn)
        for (int ks = 0; ks < 2; ++ks) {
            bf16x8 bv = *(const bf16x8*)&vs[16 * tn + ln][ks * 32 + quad * 8];
            acc2[tn] = __builtin_amdgcn_mfma_f32_16x16x32_bf16(ap[ks], bv, acc2[tn], 0, 0, 0);
        }

    // store: attnout[(b*64+n)*1024 + h*64 + d]
    bf16* dst = attnout + (size_t)b * HW * CH + h * HDIM;
    for (int r = 0; r < 4; ++r) {
        int n = 16 * w + quad * 4 + r;
        for (int tn = 0; tn < 4; ++tn)
            dst[(size_t)n * CH + 16 * tn + ln] = (bf16)acc2[tn][r];
    }
}

// ---------------- proj GEMM + bias + gamma blend + LN partial stats ----------------
// D[pix][o] = sum_c AO[pix][c] * Wp[o][c]; v = g*(D+bp) + (1-g)*x; stats[b] += (sum, sumsq)
// out_ws is written in y-layout [b][c][hw] fp32 via f32x4 stores (r-consecutive rows = hw)

__global__ __launch_bounds__(256) void gemm_proj(const bf16* __restrict__ AO,   // [PIX][1024]
                                                 const bf16* __restrict__ Wp,   // [1024][1024]
                                                 const float* __restrict__ bp,
                                                 const float* __restrict__ x,   // [B][C][HW] fp32
                                                 const float* __restrict__ gamma,
                                                 float* __restrict__ out_ws,    // [B][C][HW] fp32
                                                 float* __restrict__ stats) {   // [B][2]
    __shared__ bf16 As[128 * 64];
    __shared__ bf16 Bs[128 * 64];
    const int t = threadIdx.x;
    const int o0 = blockIdx.x * 128;    // over 1024 (8 tiles)
    const int pix0 = blockIdx.y * 128;  // over 65536 (512 tiles)
    const int w = t >> 6, lane = t & 63, quad = lane >> 4, ln = lane & 15;
    const int wm = w & 1, wn = w >> 1;
    const int sw = ln & 7;

    f32x4 acc[4][4];
    for (int i = 0; i < 4; ++i)
        for (int j = 0; j < 4; ++j)
            acc[i][j] = (f32x4){0.f, 0.f, 0.f, 0.f};

    for (int kk = 0; kk < KDIM; kk += 64) {
        __syncthreads();
        const bf16* gA = AO + (size_t)pix0 * KDIM + kk;
        const bf16* gB = Wp + (size_t)o0 * KDIM + kk;
        for (int it = 0; it < 4; ++it) {
            int s = (w * 4 + it) * 64 + lane;
            int row = s >> 3;
            int c = (s & 7) ^ (row & 7);
            bf16* ldsbase = &As[(size_t)(w * 4 + it) * 64 * 8];
            async_copy16(ldsbase, gA + (size_t)row * KDIM + c * 8);
            bf16* ldsbaseB = &Bs[(size_t)(w * 4 + it) * 64 * 8];
            async_copy16(ldsbaseB, gB + (size_t)row * KDIM + c * 8);
        }
        __syncthreads();
        bf16x8 af[4][2], bb[4][2];
        for (int tm = 0; tm < 4; ++tm)
            for (int ks = 0; ks < 2; ++ks) {
                int r = 64 * wm + 16 * tm + ln;
                af[tm][ks] = *(const bf16x8*)&As[r * 64 + (((ks * 4 + quad) ^ sw) * 8)];
            }
        for (int tn = 0; tn < 4; ++tn)
            for (int ks = 0; ks < 2; ++ks) {
                int r = 64 * wn + 16 * tn + ln;
                bb[tn][ks] = *(const bf16x8*)&Bs[r * 64 + (((ks * 4 + quad) ^ sw) * 8)];
            }
        for (int tm = 0; tm < 4; ++tm)
            for (int tn = 0; tn < 4; ++tn) {
                acc[tm][tn] = __builtin_amdgcn_mfma_f32_16x16x32_bf16(af[tm][0], bb[tn][0], acc[tm][tn], 0, 0, 0);
                acc[tm][tn] = __builtin_amdgcn_mfma_f32_16x16x32_bf16(af[tm][1], bb[tn][1], acc[tm][tn], 0, 0, 0);
            }
    }

    float g = gamma[0];
    float bvx[4];
    for (int tn = 0; tn < 4; ++tn) bvx[tn] = bp[o0 + 64 * wn + 16 * tn + ln];
    int bidx = (pix0 + 64 * wm) >> 6;   // wave's 64 pix rows are one batch
    float sum = 0.f, ss = 0.f;
    for (int tm = 0; tm < 4; ++tm) {
        int hw0 = 16 * tm + 4 * quad;   // rows r=0..3 -> consecutive hw
        for (int tn = 0; tn < 4; ++tn) {
            int col = o0 + 64 * wn + 16 * tn + ln;
            size_t base = ((size_t)bidx * CH + col) * HW + hw0;
            f32x4 xr = *(const f32x4*)&x[base];
            f32x4 o;
            for (int r = 0; r < 4; ++r) {
                float v = acc[tm][tn][r] + bvx[tn];
                v = g * v + (1.0f - g) * xr[r];
                o[r] = v;
                sum += v;
                ss += v * v;
            }
            *(f32x4*)&out_ws[base] = o;   // y-layout store, 16B
        }
    }
    for (int mask = 1; mask < 64; mask <<= 1) {
        sum += __shfl_xor(sum, mask);
        ss  += __shfl_xor(ss, mask);
    }
    if (lane == 0) {
        atomicAdd(&stats[2 * bidx], sum);
        atomicAdd(&stats[2 * bidx + 1], ss);
    }
}

// ---------------- LayerNorm finalize (out_ws is y-layout -> fully coalesced f32x4) --------
__global__ void ln_kernel(const float* __restrict__ out_ws, const float* __restrict__ stats,
                          const float* __restrict__ lnw, const float* __restrict__ lnb,
                          float* __restrict__ y) {
    const size_t total = (size_t)BATCH * CH * HW;
    const float invN = 1.0f / (float)(CH * HW);
    for (size_t i = ((size_t)blockIdx.x * 256 + threadIdx.x) * 4; i < total; i += (size_t)gridDim.x * 1024) {
        int b = (int)(i >> 16);
        int rem = (int)(i & 65535);
        float mean = stats[2 * b] * invN;
        float var = stats[2 * b + 1] * invN - mean * mean;
        float rstd = rsqrtf(var + LN_EPS);
        f32x4 v = *(const f32x4*)&out_ws[i];
        f32x4 wv = *(const f32x4*)&lnw[rem];
        f32x4 bv4 = *(const f32x4*)&lnb[rem];
        f32x4 o;
        for (int j = 0; j < 4; ++j) o[j] = (v[j] - mean) * rstd * wv[j] + bv4[j];
        *(f32x4*)&y[i] = o;
    }
}

// ---------------- launch ----------------
extern "C" void kernel_launch(void* const* d_in, const int* in_sizes, int n_in,
                              void* d_out, int out_size, void* d_ws, size_t ws_size,
                              hipStream_t stream) {
    const float* x     = (const float*)d_in[0];
    const float* Wq    = (const float*)d_in[1];
    const float* bq    = (const float*)d_in[2];
    const float* Wk    = (const float*)d_in[3];
    const float* bk    = (const float*)d_in[4];
    const float* Wv    = (const float*)d_in[5];
    const float* bv    = (const float*)d_in[6];
    const float* Wp    = (const float*)d_in[7];
    const float* bp    = (const float*)d_in[8];
    const float* gamma = (const float*)d_in[9];
    const float* temp  = (const float*)d_in[10];
    const float* lnw   = (const float*)d_in[11];
    const float* lnb   = (const float*)d_in[12];
    float* y = (float*)d_out;

    char* ws = (char*)d_ws;
    // workspace layout (bytes)
    const size_t off_wqkv = 0;                               // 3072*1024*2 = 6291456
    const size_t off_wp   = 6291456;                         // 1024*1024*2 = 2097152
    const size_t off_bias = off_wp + 2097152;                // 3072*4 = 12288
    const size_t off_stat = off_bias + 12288;                // 1024*2*4 = 8192
    const size_t off_xT   = off_stat + 8192;                 // 65536*1024*2 = 134217728
    const size_t off_qkv  = off_xT + 134217728;              // 65536*3072*2 = 402653184
    const size_t off_ao   = off_qkv + 402653184;             // 65536*1024*2 = 134217728
    const size_t off_out  = off_qkv;                         // alias: qkv dead after attention

    bf16*  wqkv_b = (bf16*)(ws + off_wqkv);
    bf16*  wp_b   = (bf16*)(ws + off_wp);
    float* bias_q = (float*)(ws + off_bias);
    float* stats  = (float*)(ws + off_stat);
    bf16*  xT     = (bf16*)(ws + off_xT);
    bf16*  qkv    = (bf16*)(ws + off_qkv);
    bf16*  ao     = (bf16*)(ws + off_ao);
    float* out_ws = (float*)(ws + off_out);

    const int wn = 1024 * 1024;
    cvt_f32_bf16<<<4096, 256, 0, stream>>>(Wq, wqkv_b, wn);
    cvt_f32_bf16<<<4096, 256, 0, stream>>>(Wk, wqkv_b + (size_t)wn, wn);
    cvt_f32_bf16<<<4096, 256, 0, stream>>>(Wv, wqkv_b + (size_t)2 * wn, wn);
    cvt_f32_bf16<<<4096, 256, 0, stream>>>(Wp, wp_b, wn);
    pack_bias<<<12, 256, 0, stream>>>(bq, bk, bv, bias_q);
    transpose_x<<<dim3(32, 1024), 256, 0, stream>>>(x, xT);
    gemm_qkv<<<dim3(256), 512, 0, stream>>>(xT, wqkv_b, bias_q, qkv);
    attn_kernel<<<dim3(16, 1024), 256, 0, stream>>>(qkv, ao, temp);
    hipMemsetAsync(stats, 0, 8192, stream);
    gemm_proj<<<dim3(8, 512), 256, 0, stream>>>(ao, wp_b, bp, x, gamma, out_ws, stats);
    ln_kernel<<<16384, 256, 0, stream>>>(out_ws, stats, lnw, lnb, y);
}

// Round 5
// 1399.426 us; speedup vs baseline: 1.6512x; 1.6512x over previous
//
// v4: R1-gemm_qkv + R2-rest recombination (resubmit; R3/R4 were infra failures)
#include <hip/hip_runtime.h>

// Problem constants (B=1024, C=1024, H=W=8 -> HW=64, 16 heads, hd=64)
#define BATCH 1024
#define CH    1024
#define HW    64
#define NHEAD 16
#define HDIM  64
#define PIX   (BATCH*HW)          // 65536
#define KDIM  1024
#define LN_EPS 1e-5f
#define NORM_EPS 1e-12f
#define TEMP_EPS 1e-6f

typedef __bf16 bf16;
typedef __bf16 bf16x8 __attribute__((ext_vector_type(8)));
typedef float  f32x4  __attribute__((ext_vector_type(4)));

// async global->LDS 16B copy: LDS dest is wave-uniform base + lane*16
__device__ __forceinline__ void async_copy16(bf16* lds, const bf16* g) {
    __builtin_amdgcn_global_load_lds((const __attribute__((address_space(1))) void*)g,
                                     (__attribute__((address_space(3))) void*)lds, 16, 0, 0);
}

// ---------------- prep kernels ----------------

__global__ void cvt_f32_bf16(const float* __restrict__ src, bf16* __restrict__ dst, int n) {
    int i = blockIdx.x * 256 + threadIdx.x;
    if (i < n) dst[i] = (bf16)src[i];
}

__global__ void pack_bias(const float* __restrict__ bq, const float* __restrict__ bk,
                          const float* __restrict__ bv, float* __restrict__ dst) {
    int i = blockIdx.x * 256 + threadIdx.x;
    if (i < 1024)      dst[i] = bq[i];
    else if (i < 2048) dst[i] = bk[i - 1024];
    else if (i < 3072) dst[i] = bv[i - 2048];
}

// x[b][c][hw] fp32 -> xT[pix][c] bf16  (pix = b*64+hw), LDS transpose, both sides coalesced
__global__ void transpose_x(const float* __restrict__ x, bf16* __restrict__ xT) {
    __shared__ float tile[32][65];
    int b = blockIdx.y, ct = blockIdx.x, t = threadIdx.x;
    const float* xb = x + (size_t)b * (CH*HW) + (size_t)ct * 32 * HW;
    for (int it = 0; it < 8; ++it) {
        int cl = (t >> 6) + it * 4;
        int hw = t & 63;
        tile[cl][hw] = xb[cl * HW + hw];
    }
    __syncthreads();
    bf16* dst = xT + (size_t)b * HW * KDIM + ct * 32;
    // vectorized stores: each thread packs 4 consecutive c -> 8B store
    for (int it = 0; it < 2; ++it) {
        int hw = (t >> 3) + it * 32;
        int g4 = t & 7;
        bf16 p4[4];
        for (int j = 0; j < 4; ++j) p4[j] = (bf16)tile[4 * g4 + j][hw];
        *(uint2*)&dst[(size_t)hw * KDIM + 4 * g4] = *(uint2*)p4;
    }
}

// ---------------- GEMM qkv: 256x256 tile, 8-phase counted-vmcnt schedule ----------------
// (R1-measured version: 447 us, MfmaUtil 41%, bank-conflict 0. Do not perturb.)
// D[pix][o] = sum_k xT[pix][k] * W[o][k] + bias[o]   out [PIX][3072] bf16
// 512 threads = 8 waves (2M x 4N); per-wave 128x64 output (8x4 16x16x32 MFMA frags).
// LDS 128 KiB: sm[dbuf][A/B][half][128*64] bf16. Chunk-XOR swizzle (slot c^(r&7)),
// staged via global_load_lds w=16 with pre-swizzled global source (both-sides swizzle).
// Per iteration: 2 K-tiles, 8 phases; 1 half-tile (16KB) staged per phase;
// s_waitcnt vmcnt(6) only at phases 3 and 7 (3 half-tiles always in flight).

#define READ_A(buf, qm) \
    { _Pragma("unroll") \
      for (int tm = 0; tm < 4; ++tm) { \
        _Pragma("unroll") \
        for (int ks = 0; ks < 2; ++ks) { \
          const int r_ = (qm)*64 + tm*16 + ln; \
          af[tm][ks] = *(const bf16x8*)&sm[buf][0][wm][r_*64 + (((ks*4 + quad) ^ (ln & 7)) * 8)]; \
        } } }

#define READ_B(buf, tn0, tn1) \
    { _Pragma("unroll") \
      for (int tn = (tn0); tn < (tn1); ++tn) { \
        _Pragma("unroll") \
        for (int ks = 0; ks < 2; ++ks) { \
          const int r_ = (wn & 1)*64 + tn*16 + ln; \
          bb[tn][ks] = *(const bf16x8*)&sm[buf][1][wn >> 1][r_*64 + (((ks*4 + quad) ^ (ln & 7)) * 8)]; \
        } } }

#define MMAQ(qm, qn) \
    { __builtin_amdgcn_s_setprio(1); \
      _Pragma("unroll") \
      for (int tm = 0; tm < 4; ++tm) { \
        _Pragma("unroll") \
        for (int tn2 = 0; tn2 < 2; ++tn2) { \
          const int tn_ = (qn)*2 + tn2; \
          acc[(qm)*4 + tm][tn_] = __builtin_amdgcn_mfma_f32_16x16x32_bf16(af[tm][0], bb[tn_][0], acc[(qm)*4 + tm][tn_], 0, 0, 0); \
          acc[(qm)*4 + tm][tn_] = __builtin_amdgcn_mfma_f32_16x16x32_bf16(af[tm][1], bb[tn_][1], acc[(qm)*4 + tm][tn_], 0, 0, 0); \
        } } \
      __builtin_amdgcn_s_setprio(0); }

// one half-tile = 128 rows x 64 k (16 KB); 512 thr x 2 x 16B. op: 0=A(xT rows=pix), 1=B(W rows=o)
#define STAGE(buf, op, half, kt) \
    { const int kt_ = (kt) & 15; \
      const bf16* g_ = ((op) == 0) \
          ? Ap  + (size_t)(pix0 + (half)*128) * KDIM + kt_*64 \
          : Wqk + (size_t)(o0   + (half)*128) * KDIM + kt_*64; \
      bf16* lb_ = &sm[buf][op][half][0]; \
      _Pragma("unroll") \
      for (int l = 0; l < 2; ++l) { \
        const int s_ = (l*8 + w)*64 + lane; \
        const int row_ = s_ >> 3, cc_ = (s_ & 7) ^ (row_ & 7); \
        async_copy16(lb_ + (l*8 + w)*512, g_ + (size_t)row_*KDIM + cc_*8); \
      } }

#define BAR()   __builtin_amdgcn_s_barrier()
#define LGKM0() asm volatile("s_waitcnt lgkmcnt(0)" ::: "memory")
#define VM6()   asm volatile("s_waitcnt vmcnt(6)" ::: "memory")

__global__ __launch_bounds__(512, 2) void gemm_qkv(const bf16* __restrict__ Ap,   // xT [PIX][1024]
                                                   const bf16* __restrict__ Wqk,  // [3072][1024]
                                                   const float* __restrict__ bias,
                                                   bf16* __restrict__ out) {      // [PIX][3072]
    __shared__ bf16 sm[2][2][2][128 * 64];   // [dbuf][A/B][half] -> 128 KiB
    const int t = threadIdx.x;
    // XCD-bijective swizzle: nwg=3072 (3072%8==0). pix-tile fastest within an XCD chunk
    // so ~32 consecutive resident blocks share one B-tile (512 KB, L2-hot).
    const int bid = (blockIdx.x & 7) * 384 + (blockIdx.x >> 3);
    const int pix0 = (bid & 255) * 256;      // 256 pix tiles over 65536
    const int o0   = (bid >> 8) * 256;       // 12 o tiles over 3072
    const int w = t >> 6, lane = t & 63, quad = lane >> 4, ln = lane & 15;
    const int wm = w >> 2, wn = w & 3;       // 2 x 4 wave grid

    f32x4 acc[8][4];
#pragma unroll
    for (int i = 0; i < 8; ++i)
#pragma unroll
        for (int j = 0; j < 4; ++j)
            acc[i][j] = (f32x4){0.f, 0.f, 0.f, 0.f};

    bf16x8 af[4][2], bb[4][2];

    // prologue: stage K-tile0 fully (ht0-3) + K-tile1's Bh0,Bh1,Ah0 (ht4-6); wait oldest 8
    STAGE(0, 1, 0, 0);  // ht0: buf0.B.h0
    STAGE(0, 1, 1, 0);  // ht1: buf0.B.h1
    STAGE(0, 0, 0, 0);  // ht2: buf0.A.h0
    STAGE(0, 0, 1, 0);  // ht3: buf0.A.h1
    STAGE(1, 1, 0, 1);  // ht4: buf1.B.h0
    STAGE(1, 1, 1, 1);  // ht5: buf1.B.h1
    STAGE(1, 0, 0, 1);  // ht6: buf1.A.h0
    VM6();              // 14 outstanding -> wait 8 oldest = K-tile0 landed
    BAR();

    for (int it = 0; it < 8; ++it) {
        const int k0 = 2 * it;
        // ---- phase 0: compute buf0 quad(0,0); stage ht 8it+7 = buf1.A.h1 ----
        READ_A(0, 0);
        if (wn < 2) { READ_B(0, 0, 4); } else { READ_B(0, 0, 2); }
        STAGE(1, 0, 1, k0 + 1);
        BAR(); LGKM0(); MMAQ(0, 0); BAR();
        // ---- phase 1: quad(0,1); stage buf0.B.h0 (K-tile k0+2) ----
        if (wn >= 2) { READ_B(0, 2, 4); }
        STAGE(0, 1, 0, k0 + 2);
        BAR(); LGKM0(); MMAQ(0, 1); BAR();
        // ---- phase 2: quad(1,1); stage buf0.B.h1 ----
        READ_A(0, 1);
        STAGE(0, 1, 1, k0 + 2);
        BAR(); LGKM0(); MMAQ(1, 1); BAR();
        // ---- phase 3: quad(1,0); stage buf0.A.h0; counted wait for K-tile k0+1 ----
        STAGE(0, 0, 0, k0 + 2);
        VM6();
        BAR(); LGKM0(); MMAQ(1, 0); BAR();
        // ---- phase 4: compute buf1 quad(0,0); stage buf0.A.h1 ----
        READ_A(1, 0);
        if (wn < 2) { READ_B(1, 0, 4); } else { READ_B(1, 0, 2); }
        STAGE(0, 0, 1, k0 + 2);
        BAR(); LGKM0(); MMAQ(0, 0); BAR();
        // ---- phase 5: quad(0,1); stage buf1.B.h0 (K-tile k0+3) ----
        if (wn >= 2) { READ_B(1, 2, 4); }
        STAGE(1, 1, 0, k0 + 3);
        BAR(); LGKM0(); MMAQ(0, 1); BAR();
        // ---- phase 6: quad(1,1); stage buf1.B.h1 ----
        READ_A(1, 1);
        STAGE(1, 1, 1, k0 + 3);
        BAR(); LGKM0(); MMAQ(1, 1); BAR();
        // ---- phase 7: quad(1,0); stage buf1.A.h0; counted wait for K-tile k0+2 ----
        STAGE(1, 0, 0, k0 + 3);
        VM6();
        BAR(); LGKM0(); MMAQ(1, 0); BAR();
    }

    asm volatile("s_waitcnt vmcnt(0)" ::: "memory");   // drain tail stages before exit
    float bvv[4];
#pragma unroll
    for (int tn = 0; tn < 4; ++tn) bvv[tn] = bias[o0 + 64 * wn + 16 * tn + ln];
#pragma unroll
    for (int tm = 0; tm < 8; ++tm)
#pragma unroll
        for (int r = 0; r < 4; ++r) {
            int row = pix0 + 128 * wm + 16 * tm + quad * 4 + r;
#pragma unroll
            for (int tn = 0; tn < 4; ++tn) {
                int col = o0 + 64 * wn + 16 * tn + ln;
                out[(size_t)row * 3072 + col] = (bf16)(acc[tm][tn][r] + bvv[tn]);
            }
        }
}

// ---------------- attention per (b, h) ----------------
// qkv layout: [pix][3072]  (q: cols h*64+d, k: 1024+h*64+d, v: 2048+h*64+d)
// normalize q,k over spatial dim n; attn = softmax((q.k)/(T+eps)); out[n][d] -> attnout[pix][c]

__global__ __launch_bounds__(256) void attn_kernel(const bf16* __restrict__ qkv,
                                                   bf16* __restrict__ attnout,
                                                   const float* __restrict__ temp) {
    __shared__ bf16 qs[64][72];
    __shared__ bf16 ksld[64][72];
    __shared__ bf16 vs[64][72];   // transposed: vs[d][m]
    __shared__ bf16 ps[64][72];   // softmax probs [n][m]
    __shared__ float rsq[64], rsk[64];

    int h = blockIdx.x, b = blockIdx.y, t = threadIdx.x;
    int w = t >> 6, lane = t & 63, quad = lane >> 4, ln = lane & 15;
    const bf16* base = qkv + (size_t)b * HW * 3072 + h * HDIM;

    // stage q, k: rows = spatial n, cols = d (contiguous)
    for (int it = 0; it < 2; ++it) {
        int row = (t >> 3) + it * 32, ch = t & 7;
        *(uint4*)&qs[row][ch * 8]   = *(const uint4*)&base[(size_t)row * 3072 + ch * 8];
        *(uint4*)&ksld[row][ch * 8] = *(const uint4*)&base[(size_t)row * 3072 + 1024 + ch * 8];
    }
    // stage v transposed -> vs[d][m]
    for (int it = 0; it < 2; ++it) {
        int m = t & 63, dg = (t >> 6) * 8 + it * 32;
        uint4 v4 = *(const uint4*)&base[(size_t)m * 3072 + 2048 + dg];
        bf16 tmpv[8];
        *(uint4*)tmpv = v4;
        for (int j = 0; j < 8; ++j) vs[dg + j][m] = tmpv[j];
    }
    __syncthreads();

    // l2 norms over n for each d: all 256 threads (each sums 32 rows, pair-combine)
    {
        int d = (t >> 1) & 63, seg = t & 1;
        float ssum = 0.f;
        if (t < 128) {
            for (int n = seg * 32; n < seg * 32 + 32; ++n) { float v = (float)qs[n][d]; ssum += v * v; }
        } else {
            for (int n = seg * 32; n < seg * 32 + 32; ++n) { float v = (float)ksld[n][d]; ssum += v * v; }
        }
        ssum += __shfl_xor(ssum, 1);
        if (seg == 0) {
            float r = 1.0f / fmaxf(sqrtf(ssum), NORM_EPS);
            if (t < 128) rsq[d] = r; else rsk[d] = r;
        }
    }
    __syncthreads();
    for (int it = 0; it < 16; ++it) {
        int e = t + 256 * it;
        int n = e >> 6, d = e & 63;
        qs[n][d]   = (bf16)((float)qs[n][d] * rsq[d]);
        ksld[n][d] = (bf16)((float)ksld[n][d] * rsk[d]);
    }
    __syncthreads();

    // QK^T: attn[n][m] = sum_d q[d][n] k[d][m];  wave w -> rows n in [16w,16w+16)
    f32x4 acc[4];
    for (int i = 0; i < 4; ++i) acc[i] = (f32x4){0.f, 0.f, 0.f, 0.f};
    bf16x8 aq[2];
    for (int ks = 0; ks < 2; ++ks)
        aq[ks] = *(const bf16x8*)&qs[16 * w + ln][ks * 32 + quad * 8];
    for (int tn = 0; tn < 4; ++tn)
        for (int ks = 0; ks < 2; ++ks) {
            bf16x8 bk = *(const bf16x8*)&ksld[16 * tn + ln][ks * 32 + quad * 8];
            acc[tn] = __builtin_amdgcn_mfma_f32_16x16x32_bf16(aq[ks], bk, acc[tn], 0, 0, 0);
        }

    float invt = 1.0f / (temp[0] + TEMP_EPS);
    for (int r = 0; r < 4; ++r) {
        float v[4];
        for (int tn = 0; tn < 4; ++tn) v[tn] = acc[tn][r] * invt;
        float mx = fmaxf(fmaxf(v[0], v[1]), fmaxf(v[2], v[3]));
        for (int mask = 1; mask < 16; mask <<= 1) mx = fmaxf(mx, __shfl_xor(mx, mask));
        float p[4], s = 0.f;
        for (int tn = 0; tn < 4; ++tn) { p[tn] = __expf(v[tn] - mx); s += p[tn]; }
        for (int mask = 1; mask < 16; mask <<= 1) s += __shfl_xor(s, mask);
        float inv = 1.0f / s;
        int n = 16 * w + quad * 4 + r;
        for (int tn = 0; tn < 4; ++tn)
            ps[n][16 * tn + ln] = (bf16)(p[tn] * inv);
    }
    __syncthreads();

    // PV: out[n][d] = sum_m attn[n][m] v[d][m]
    f32x4 acc2[4];
    for (int i = 0; i < 4; ++i) acc2[i] = (f32x4){0.f, 0.f, 0.f, 0.f};
    bf16x8 ap[2];
    for (int ks = 0; ks < 2; ++ks)
        ap[ks] = *(const bf16x8*)&ps[16 * w + ln][ks * 32 + quad * 8];
    for (int tn = 0; tn < 4; ++tn)
        for (int ks = 0; ks < 2; ++ks) {
            bf16x8 bv = *(const bf16x8*)&vs[16 * tn + ln][ks * 32 + quad * 8];
            acc2[tn] = __builtin_amdgcn_mfma_f32_16x16x32_bf16(ap[ks], bv, acc2[tn], 0, 0, 0);
        }

    // store: attnout[(b*64+n)*1024 + h*64 + d]
    bf16* dst = attnout + (size_t)b * HW * CH + h * HDIM;
    for (int r = 0; r < 4; ++r) {
        int n = 16 * w + quad * 4 + r;
        for (int tn = 0; tn < 4; ++tn)
            dst[(size_t)n * CH + 16 * tn + ln] = (bf16)acc2[tn][r];
    }
}

// ---------------- proj GEMM + bias + gamma blend + LN partial stats ----------------
// D[pix][o] = sum_c AO[pix][c] * Wp[o][c]; v = g*(D+bp) + (1-g)*x; stats[b] += (sum, sumsq)
// out_ws is written in y-layout [b][c][hw] fp32 via f32x4 stores (r-consecutive rows = hw)

__global__ __launch_bounds__(256) void gemm_proj(const bf16* __restrict__ AO,   // [PIX][1024]
                                                 const bf16* __restrict__ Wp,   // [1024][1024]
                                                 const float* __restrict__ bp,
                                                 const float* __restrict__ x,   // [B][C][HW] fp32
                                                 const float* __restrict__ gamma,
                                                 float* __restrict__ out_ws,    // [B][C][HW] fp32
                                                 float* __restrict__ stats) {   // [B][2]
    __shared__ bf16 As[128 * 64];
    __shared__ bf16 Bs[128 * 64];
    const int t = threadIdx.x;
    const int o0 = blockIdx.x * 128;    // over 1024 (8 tiles)
    const int pix0 = blockIdx.y * 128;  // over 65536 (512 tiles)
    const int w = t >> 6, lane = t & 63, quad = lane >> 4, ln = lane & 15;
    const int wm = w & 1, wn = w >> 1;
    const int sw = ln & 7;

    f32x4 acc[4][4];
    for (int i = 0; i < 4; ++i)
        for (int j = 0; j < 4; ++j)
            acc[i][j] = (f32x4){0.f, 0.f, 0.f, 0.f};

    for (int kk = 0; kk < KDIM; kk += 64) {
        __syncthreads();
        const bf16* gA = AO + (size_t)pix0 * KDIM + kk;
        const bf16* gB = Wp + (size_t)o0 * KDIM + kk;
        for (int it = 0; it < 4; ++it) {
            int s = (w * 4 + it) * 64 + lane;
            int row = s >> 3;
            int c = (s & 7) ^ (row & 7);
            bf16* ldsbase = &As[(size_t)(w * 4 + it) * 64 * 8];
            async_copy16(ldsbase, gA + (size_t)row * KDIM + c * 8);
            bf16* ldsbaseB = &Bs[(size_t)(w * 4 + it) * 64 * 8];
            async_copy16(ldsbaseB, gB + (size_t)row * KDIM + c * 8);
        }
        __syncthreads();
        bf16x8 af[4][2], bb[4][2];
        for (int tm = 0; tm < 4; ++tm)
            for (int ks = 0; ks < 2; ++ks) {
                int r = 64 * wm + 16 * tm + ln;
                af[tm][ks] = *(const bf16x8*)&As[r * 64 + (((ks * 4 + quad) ^ sw) * 8)];
            }
        for (int tn = 0; tn < 4; ++tn)
            for (int ks = 0; ks < 2; ++ks) {
                int r = 64 * wn + 16 * tn + ln;
                bb[tn][ks] = *(const bf16x8*)&Bs[r * 64 + (((ks * 4 + quad) ^ sw) * 8)];
            }
        for (int tm = 0; tm < 4; ++tm)
            for (int tn = 0; tn < 4; ++tn) {
                acc[tm][tn] = __builtin_amdgcn_mfma_f32_16x16x32_bf16(af[tm][0], bb[tn][0], acc[tm][tn], 0, 0, 0);
                acc[tm][tn] = __builtin_amdgcn_mfma_f32_16x16x32_bf16(af[tm][1], bb[tn][1], acc[tm][tn], 0, 0, 0);
            }
    }

    float g = gamma[0];
    float bvx[4];
    for (int tn = 0; tn < 4; ++tn) bvx[tn] = bp[o0 + 64 * wn + 16 * tn + ln];
    int bidx = (pix0 + 64 * wm) >> 6;   // wave's 64 pix rows are one batch
    float sum = 0.f, ss = 0.f;
    for (int tm = 0; tm < 4; ++tm) {
        int hw0 = 16 * tm + 4 * quad;   // rows r=0..3 -> consecutive hw
        for (int tn = 0; tn < 4; ++tn) {
            int col = o0 + 64 * wn + 16 * tn + ln;
            size_t base = ((size_t)bidx * CH + col) * HW + hw0;
            f32x4 xr = *(const f32x4*)&x[base];
            f32x4 o;
            for (int r = 0; r < 4; ++r) {
                float v = acc[tm][tn][r] + bvx[tn];
                v = g * v + (1.0f - g) * xr[r];
                o[r] = v;
                sum += v;
                ss += v * v;
            }
            *(f32x4*)&out_ws[base] = o;   // y-layout store, 16B
        }
    }
    for (int mask = 1; mask < 64; mask <<= 1) {
        sum += __shfl_xor(sum, mask);
        ss  += __shfl_xor(ss, mask);
    }
    if (lane == 0) {
        atomicAdd(&stats[2 * bidx], sum);
        atomicAdd(&stats[2 * bidx + 1], ss);
    }
}

// ---------------- LayerNorm finalize (out_ws is y-layout -> fully coalesced f32x4) --------
__global__ void ln_kernel(const float* __restrict__ out_ws, const float* __restrict__ stats,
                          const float* __restrict__ lnw, const float* __restrict__ lnb,
                          float* __restrict__ y) {
    const size_t total = (size_t)BATCH * CH * HW;
    const float invN = 1.0f / (float)(CH * HW);
    for (size_t i = ((size_t)blockIdx.x * 256 + threadIdx.x) * 4; i < total; i += (size_t)gridDim.x * 1024) {
        int b = (int)(i >> 16);
        int rem = (int)(i & 65535);
        float mean = stats[2 * b] * invN;
        float var = stats[2 * b + 1] * invN - mean * mean;
        float rstd = rsqrtf(var + LN_EPS);
        f32x4 v = *(const f32x4*)&out_ws[i];
        f32x4 wv = *(const f32x4*)&lnw[rem];
        f32x4 bv4 = *(const f32x4*)&lnb[rem];
        f32x4 o;
        for (int j = 0; j < 4; ++j) o[j] = (v[j] - mean) * rstd * wv[j] + bv4[j];
        *(f32x4*)&y[i] = o;
    }
}

// ---------------- launch ----------------
extern "C" void kernel_launch(void* const* d_in, const int* in_sizes, int n_in,
                              void* d_out, int out_size, void* d_ws, size_t ws_size,
                              hipStream_t stream) {
    const float* x     = (const float*)d_in[0];
    const float* Wq    = (const float*)d_in[1];
    const float* bq    = (const float*)d_in[2];
    const float* Wk    = (const float*)d_in[3];
    const float* bk    = (const float*)d_in[4];
    const float* Wv    = (const float*)d_in[5];
    const float* bv    = (const float*)d_in[6];
    const float* Wp    = (const float*)d_in[7];
    const float* bp    = (const float*)d_in[8];
    const float* gamma = (const float*)d_in[9];
    const float* temp  = (const float*)d_in[10];
    const float* lnw   = (const float*)d_in[11];
    const float* lnb   = (const float*)d_in[12];
    float* y = (float*)d_out;

    char* ws = (char*)d_ws;
    // workspace layout (bytes)
    const size_t off_wqkv = 0;                               // 3072*1024*2 = 6291456
    const size_t off_wp   = 6291456;                         // 1024*1024*2 = 2097152
    const size_t off_bias = off_wp + 2097152;                // 3072*4 = 12288
    const size_t off_stat = off_bias + 12288;                // 1024*2*4 = 8192
    const size_t off_xT   = off_stat + 8192;                 // 65536*1024*2 = 134217728
    const size_t off_qkv  = off_xT + 134217728;              // 65536*3072*2 = 402653184
    const size_t off_ao   = off_qkv + 402653184;             // 65536*1024*2 = 134217728
    const size_t off_out  = off_qkv;                         // alias: qkv dead after attention

    bf16*  wqkv_b = (bf16*)(ws + off_wqkv);
    bf16*  wp_b   = (bf16*)(ws + off_wp);
    float* bias_q = (float*)(ws + off_bias);
    float* stats  = (float*)(ws + off_stat);
    bf16*  xT     = (bf16*)(ws + off_xT);
    bf16*  qkv    = (bf16*)(ws + off_qkv);
    bf16*  ao     = (bf16*)(ws + off_ao);
    float* out_ws = (float*)(ws + off_out);

    const int wn = 1024 * 1024;
    cvt_f32_bf16<<<4096, 256, 0, stream>>>(Wq, wqkv_b, wn);
    cvt_f32_bf16<<<4096, 256, 0, stream>>>(Wk, wqkv_b + (size_t)wn, wn);
    cvt_f32_bf16<<<4096, 256, 0, stream>>>(Wv, wqkv_b + (size_t)2 * wn, wn);
    cvt_f32_bf16<<<4096, 256, 0, stream>>>(Wp, wp_b, wn);
    pack_bias<<<12, 256, 0, stream>>>(bq, bk, bv, bias_q);
    transpose_x<<<dim3(32, 1024), 256, 0, stream>>>(x, xT);
    gemm_qkv<<<dim3(3072), 512, 0, stream>>>(xT, wqkv_b, bias_q, qkv);
    attn_kernel<<<dim3(16, 1024), 256, 0, stream>>>(qkv, ao, temp);
    hipMemsetAsync(stats, 0, 8192, stream);
    gemm_proj<<<dim3(8, 512), 256, 0, stream>>>(ao, wp_b, bp, x, gamma, out_ws, stats);
    ln_kernel<<<16384, 256, 0, stream>>>(out_ws, stats, lnw, lnb, y);
}

// Round 6
// 1393.982 us; speedup vs baseline: 1.6577x; 1.0039x over previous
//
// v6: freeze gemm_qkv/gemm_proj/ln; attn reg-scale norm (-2 barriers), vec transpose, fused cvt
#include <hip/hip_runtime.h>

// Problem constants (B=1024, C=1024, H=W=8 -> HW=64, 16 heads, hd=64)
#define BATCH 1024
#define CH    1024
#define HW    64
#define NHEAD 16
#define HDIM  64
#define PIX   (BATCH*HW)          // 65536
#define KDIM  1024
#define LN_EPS 1e-5f
#define NORM_EPS 1e-12f
#define TEMP_EPS 1e-6f

typedef __bf16 bf16;
typedef __bf16 bf16x8 __attribute__((ext_vector_type(8)));
typedef float  f32x4  __attribute__((ext_vector_type(4)));

// async global->LDS 16B copy: LDS dest is wave-uniform base + lane*16
__device__ __forceinline__ void async_copy16(bf16* lds, const bf16* g) {
    __builtin_amdgcn_global_load_lds((const __attribute__((address_space(1))) void*)g,
                                     (__attribute__((address_space(3))) void*)lds, 16, 0, 0);
}

// ---------------- prep kernels ----------------

// all 4 weight matrices f32->bf16 in one launch; f32x4 loads, 8B packed stores
__global__ void cvt_all(const float* __restrict__ Wq, const float* __restrict__ Wk,
                        const float* __restrict__ Wv, const float* __restrict__ Wp,
                        bf16* __restrict__ wqkv_b, bf16* __restrict__ wp_b) {
    const int wn = 1024 * 1024;
    int which = blockIdx.x >> 10;               // 1024 blocks per matrix
    int e = ((blockIdx.x & 1023) * 256 + threadIdx.x) * 4;
    const float* src = (which == 0) ? Wq : (which == 1) ? Wk : (which == 2) ? Wv : Wp;
    bf16* dst = (which < 3) ? (wqkv_b + (size_t)which * wn) : wp_b;
    f32x4 v = *(const f32x4*)&src[e];
    bf16 p4[4];
#pragma unroll
    for (int j = 0; j < 4; ++j) p4[j] = (bf16)v[j];
    *(uint2*)&dst[e] = *(uint2*)p4;
}

__global__ void pack_bias(const float* __restrict__ bq, const float* __restrict__ bk,
                          const float* __restrict__ bv, float* __restrict__ dst) {
    int i = blockIdx.x * 256 + threadIdx.x;
    if (i < 1024)      dst[i] = bq[i];
    else if (i < 2048) dst[i] = bk[i - 1024];
    else if (i < 3072) dst[i] = bv[i - 2048];
}

// x[b][c][hw] fp32 -> xT[pix][c] bf16  (pix = b*64+hw), LDS transpose
// loads f32x4 (16B/lane, fully coalesced); pad 68 keeps vec LDS writes 16B-aligned
__global__ void transpose_x(const float* __restrict__ x, bf16* __restrict__ xT) {
    __shared__ float tile[32][68];
    int b = blockIdx.y, ct = blockIdx.x, t = threadIdx.x;
    const float* xb = x + (size_t)b * (CH*HW) + (size_t)ct * 32 * HW;
#pragma unroll
    for (int it = 0; it < 2; ++it) {
        int e = (t + it * 256) * 4;             // 0..2047, multiple of 4
        int cl = e >> 6, hw = e & 63;
        *(f32x4*)&tile[cl][hw] = *(const f32x4*)&xb[e];
    }
    __syncthreads();
    bf16* dst = xT + (size_t)b * HW * KDIM + ct * 32;
#pragma unroll
    for (int it = 0; it < 2; ++it) {
        int hw = (t >> 3) + it * 32;
        int g4 = t & 7;
        bf16 p4[4];
#pragma unroll
        for (int j = 0; j < 4; ++j) p4[j] = (bf16)tile[4 * g4 + j][hw];
        *(uint2*)&dst[(size_t)hw * KDIM + 4 * g4] = *(uint2*)p4;
    }
}

// ---------------- GEMM qkv: 256x256 tile, 8-phase counted-vmcnt schedule ----------------
// (R1/R5-measured: 452 us, MfmaUtil 41%, bank-conflict 0. FROZEN - do not perturb.)

#define READ_A(buf, qm) \
    { _Pragma("unroll") \
      for (int tm = 0; tm < 4; ++tm) { \
        _Pragma("unroll") \
        for (int ks = 0; ks < 2; ++ks) { \
          const int r_ = (qm)*64 + tm*16 + ln; \
          af[tm][ks] = *(const bf16x8*)&sm[buf][0][wm][r_*64 + (((ks*4 + quad) ^ (ln & 7)) * 8)]; \
        } } }

#define READ_B(buf, tn0, tn1) \
    { _Pragma("unroll") \
      for (int tn = (tn0); tn < (tn1); ++tn) { \
        _Pragma("unroll") \
        for (int ks = 0; ks < 2; ++ks) { \
          const int r_ = (wn & 1)*64 + tn*16 + ln; \
          bb[tn][ks] = *(const bf16x8*)&sm[buf][1][wn >> 1][r_*64 + (((ks*4 + quad) ^ (ln & 7)) * 8)]; \
        } } }

#define MMAQ(qm, qn) \
    { __builtin_amdgcn_s_setprio(1); \
      _Pragma("unroll") \
      for (int tm = 0; tm < 4; ++tm) { \
        _Pragma("unroll") \
        for (int tn2 = 0; tn2 < 2; ++tn2) { \
          const int tn_ = (qn)*2 + tn2; \
          acc[(qm)*4 + tm][tn_] = __builtin_amdgcn_mfma_f32_16x16x32_bf16(af[tm][0], bb[tn_][0], acc[(qm)*4 + tm][tn_], 0, 0, 0); \
          acc[(qm)*4 + tm][tn_] = __builtin_amdgcn_mfma_f32_16x16x32_bf16(af[tm][1], bb[tn_][1], acc[(qm)*4 + tm][tn_], 0, 0, 0); \
        } } \
      __builtin_amdgcn_s_setprio(0); }

// one half-tile = 128 rows x 64 k (16 KB); 512 thr x 2 x 16B. op: 0=A(xT rows=pix), 1=B(W rows=o)
#define STAGE(buf, op, half, kt) \
    { const int kt_ = (kt) & 15; \
      const bf16* g_ = ((op) == 0) \
          ? Ap  + (size_t)(pix0 + (half)*128) * KDIM + kt_*64 \
          : Wqk + (size_t)(o0   + (half)*128) * KDIM + kt_*64; \
      bf16* lb_ = &sm[buf][op][half][0]; \
      _Pragma("unroll") \
      for (int l = 0; l < 2; ++l) { \
        const int s_ = (l*8 + w)*64 + lane; \
        const int row_ = s_ >> 3, cc_ = (s_ & 7) ^ (row_ & 7); \
        async_copy16(lb_ + (l*8 + w)*512, g_ + (size_t)row_*KDIM + cc_*8); \
      } }

#define BAR()   __builtin_amdgcn_s_barrier()
#define LGKM0() asm volatile("s_waitcnt lgkmcnt(0)" ::: "memory")
#define VM6()   asm volatile("s_waitcnt vmcnt(6)" ::: "memory")

__global__ __launch_bounds__(512, 2) void gemm_qkv(const bf16* __restrict__ Ap,   // xT [PIX][1024]
                                                   const bf16* __restrict__ Wqk,  // [3072][1024]
                                                   const float* __restrict__ bias,
                                                   bf16* __restrict__ out) {      // [PIX][3072]
    __shared__ bf16 sm[2][2][2][128 * 64];   // [dbuf][A/B][half] -> 128 KiB
    const int t = threadIdx.x;
    const int bid = (blockIdx.x & 7) * 384 + (blockIdx.x >> 3);
    const int pix0 = (bid & 255) * 256;      // 256 pix tiles over 65536
    const int o0   = (bid >> 8) * 256;       // 12 o tiles over 3072
    const int w = t >> 6, lane = t & 63, quad = lane >> 4, ln = lane & 15;
    const int wm = w >> 2, wn = w & 3;       // 2 x 4 wave grid

    f32x4 acc[8][4];
#pragma unroll
    for (int i = 0; i < 8; ++i)
#pragma unroll
        for (int j = 0; j < 4; ++j)
            acc[i][j] = (f32x4){0.f, 0.f, 0.f, 0.f};

    bf16x8 af[4][2], bb[4][2];

    STAGE(0, 1, 0, 0);
    STAGE(0, 1, 1, 0);
    STAGE(0, 0, 0, 0);
    STAGE(0, 0, 1, 0);
    STAGE(1, 1, 0, 1);
    STAGE(1, 1, 1, 1);
    STAGE(1, 0, 0, 1);
    VM6();
    BAR();

    for (int it = 0; it < 8; ++it) {
        const int k0 = 2 * it;
        READ_A(0, 0);
        if (wn < 2) { READ_B(0, 0, 4); } else { READ_B(0, 0, 2); }
        STAGE(1, 0, 1, k0 + 1);
        BAR(); LGKM0(); MMAQ(0, 0); BAR();

        if (wn >= 2) { READ_B(0, 2, 4); }
        STAGE(0, 1, 0, k0 + 2);
        BAR(); LGKM0(); MMAQ(0, 1); BAR();

        READ_A(0, 1);
        STAGE(0, 1, 1, k0 + 2);
        BAR(); LGKM0(); MMAQ(1, 1); BAR();

        STAGE(0, 0, 0, k0 + 2);
        VM6();
        BAR(); LGKM0(); MMAQ(1, 0); BAR();

        READ_A(1, 0);
        if (wn < 2) { READ_B(1, 0, 4); } else { READ_B(1, 0, 2); }
        STAGE(0, 0, 1, k0 + 2);
        BAR(); LGKM0(); MMAQ(0, 0); BAR();

        if (wn >= 2) { READ_B(1, 2, 4); }
        STAGE(1, 1, 0, k0 + 3);
        BAR(); LGKM0(); MMAQ(0, 1); BAR();

        READ_A(1, 1);
        STAGE(1, 1, 1, k0 + 3);
        BAR(); LGKM0(); MMAQ(1, 1); BAR();

        STAGE(1, 0, 0, k0 + 3);
        VM6();
        BAR(); LGKM0(); MMAQ(1, 0); BAR();
    }

    asm volatile("s_waitcnt vmcnt(0)" ::: "memory");
    float bvv[4];
#pragma unroll
    for (int tn = 0; tn < 4; ++tn) bvv[tn] = bias[o0 + 64 * wn + 16 * tn + ln];
#pragma unroll
    for (int tm = 0; tm < 8; ++tm)
#pragma unroll
        for (int r = 0; r < 4; ++r) {
            int row = pix0 + 128 * wm + 16 * tm + quad * 4 + r;
#pragma unroll
            for (int tn = 0; tn < 4; ++tn) {
                int col = o0 + 64 * wn + 16 * tn + ln;
                out[(size_t)row * 3072 + col] = (bf16)(acc[tm][tn][r] + bvv[tn]);
            }
        }
}

// ---------------- attention per (b, h) ----------------
// Normalization folded into MFMA fragments: scale rsq[d]/rsk[d] applied in registers at
// fragment load (d = ks*32+quad*8+j is the contraction index -> same rounding as LDS path).
// Barriers: stage->bar->norm->bar->QK^T->softmax->ps(wave-private rows)->PV. 2 barriers.

__global__ __launch_bounds__(256) void attn_kernel(const bf16* __restrict__ qkv,
                                                   bf16* __restrict__ attnout,
                                                   const float* __restrict__ temp) {
    __shared__ bf16 qs[64][72];
    __shared__ bf16 ksld[64][72];
    __shared__ bf16 vs[64][72];   // transposed: vs[d][m]
    __shared__ bf16 ps[64][72];   // softmax probs [n][m] (wave-private row blocks)
    __shared__ float rsq[64], rsk[64];

    int h = blockIdx.x, b = blockIdx.y, t = threadIdx.x;
    int w = t >> 6, lane = t & 63, quad = lane >> 4, ln = lane & 15;
    const bf16* base = qkv + (size_t)b * HW * 3072 + h * HDIM;

    // stage q, k: rows = spatial n, cols = d (contiguous)
#pragma unroll
    for (int it = 0; it < 2; ++it) {
        int row = (t >> 3) + it * 32, ch = t & 7;
        *(uint4*)&qs[row][ch * 8]   = *(const uint4*)&base[(size_t)row * 3072 + ch * 8];
        *(uint4*)&ksld[row][ch * 8] = *(const uint4*)&base[(size_t)row * 3072 + 1024 + ch * 8];
    }
    // stage v transposed -> vs[d][m]
#pragma unroll
    for (int it = 0; it < 2; ++it) {
        int m = t & 63, dg = (t >> 6) * 8 + it * 32;
        uint4 v4 = *(const uint4*)&base[(size_t)m * 3072 + 2048 + dg];
        bf16 tmpv[8];
        *(uint4*)tmpv = v4;
#pragma unroll
        for (int j = 0; j < 8; ++j) vs[dg + j][m] = tmpv[j];
    }
    __syncthreads();

    // l2 norms over n for each d: all 256 threads (each sums 32 rows, pair-combine)
    {
        int d = (t >> 1) & 63, seg = t & 1;
        float ssum = 0.f;
        if (t < 128) {
            for (int n = seg * 32; n < seg * 32 + 32; ++n) { float v = (float)qs[n][d]; ssum += v * v; }
        } else {
            for (int n = seg * 32; n < seg * 32 + 32; ++n) { float v = (float)ksld[n][d]; ssum += v * v; }
        }
        ssum += __shfl_xor(ssum, 1);
        if (seg == 0) {
            float r = 1.0f / fmaxf(sqrtf(ssum), NORM_EPS);
            if (t < 128) rsq[d] = r; else rsk[d] = r;
        }
    }
    __syncthreads();

    // per-lane fragment scales (fully unrolled -> static indexing, stays in VGPRs)
    float sq[16], sk[16];
#pragma unroll
    for (int ks = 0; ks < 2; ++ks)
#pragma unroll
        for (int j = 0; j < 8; ++j) {
            sq[ks * 8 + j] = rsq[ks * 32 + quad * 8 + j];
            sk[ks * 8 + j] = rsk[ks * 32 + quad * 8 + j];
        }

    // QK^T with in-register scaling: attn[n][m] = sum_d q^[n][d] k^[m][d]
    f32x4 acc[4];
#pragma unroll
    for (int i = 0; i < 4; ++i) acc[i] = (f32x4){0.f, 0.f, 0.f, 0.f};
    bf16x8 aq[2];
#pragma unroll
    for (int ks = 0; ks < 2; ++ks) {
        bf16x8 raw = *(const bf16x8*)&qs[16 * w + ln][ks * 32 + quad * 8];
#pragma unroll
        for (int j = 0; j < 8; ++j) aq[ks][j] = (bf16)((float)raw[j] * sq[ks * 8 + j]);
    }
#pragma unroll
    for (int tn = 0; tn < 4; ++tn)
#pragma unroll
        for (int ks = 0; ks < 2; ++ks) {
            bf16x8 raw = *(const bf16x8*)&ksld[16 * tn + ln][ks * 32 + quad * 8];
            bf16x8 bk;
#pragma unroll
            for (int j = 0; j < 8; ++j) bk[j] = (bf16)((float)raw[j] * sk[ks * 8 + j]);
            acc[tn] = __builtin_amdgcn_mfma_f32_16x16x32_bf16(aq[ks], bk, acc[tn], 0, 0, 0);
        }

    float invt = 1.0f / (temp[0] + TEMP_EPS);
#pragma unroll
    for (int r = 0; r < 4; ++r) {
        float v[4];
#pragma unroll
        for (int tn = 0; tn < 4; ++tn) v[tn] = acc[tn][r] * invt;
        float mx = fmaxf(fmaxf(v[0], v[1]), fmaxf(v[2], v[3]));
        for (int mask = 1; mask < 16; mask <<= 1) mx = fmaxf(mx, __shfl_xor(mx, mask));
        float p[4], s = 0.f;
#pragma unroll
        for (int tn = 0; tn < 4; ++tn) { p[tn] = __expf(v[tn] - mx); s += p[tn]; }
        for (int mask = 1; mask < 16; mask <<= 1) s += __shfl_xor(s, mask);
        float inv = 1.0f / s;
        int n = 16 * w + quad * 4 + r;
#pragma unroll
        for (int tn = 0; tn < 4; ++tn)
            ps[n][16 * tn + ln] = (bf16)(p[tn] * inv);
    }
    // no barrier: ps rows [16w,16w+16) are written and read by wave w only;
    // compiler orders same-array LDS deps via lgkmcnt.

    // PV: out[n][d] = sum_m attn[n][m] v[d][m]
    f32x4 acc2[4];
#pragma unroll
    for (int i = 0; i < 4; ++i) acc2[i] = (f32x4){0.f, 0.f, 0.f, 0.f};
    bf16x8 ap[2];
#pragma unroll
    for (int ks = 0; ks < 2; ++ks)
        ap[ks] = *(const bf16x8*)&ps[16 * w + ln][ks * 32 + quad * 8];
#pragma unroll
    for (int tn = 0; tn < 4; ++tn)
#pragma unroll
        for (int ks = 0; ks < 2; ++ks) {
            bf16x8 bv = *(const bf16x8*)&vs[16 * tn + ln][ks * 32 + quad * 8];
            acc2[tn] = __builtin_amdgcn_mfma_f32_16x16x32_bf16(ap[ks], bv, acc2[tn], 0, 0, 0);
        }

    // store: attnout[(b*64+n)*1024 + h*64 + d]
    bf16* dst = attnout + (size_t)b * HW * CH + h * HDIM;
#pragma unroll
    for (int r = 0; r < 4; ++r) {
        int n = 16 * w + quad * 4 + r;
#pragma unroll
        for (int tn = 0; tn < 4; ++tn)
            dst[(size_t)n * CH + 16 * tn + ln] = (bf16)acc2[tn][r];
    }
}

// ---------------- proj GEMM + bias + gamma blend + LN partial stats (FROZEN) ----------------

__global__ __launch_bounds__(256) void gemm_proj(const bf16* __restrict__ AO,   // [PIX][1024]
                                                 const bf16* __restrict__ Wp,   // [1024][1024]
                                                 const float* __restrict__ bp,
                                                 const float* __restrict__ x,   // [B][C][HW] fp32
                                                 const float* __restrict__ gamma,
                                                 float* __restrict__ out_ws,    // [B][C][HW] fp32
                                                 float* __restrict__ stats) {   // [B][2]
    __shared__ bf16 As[128 * 64];
    __shared__ bf16 Bs[128 * 64];
    const int t = threadIdx.x;
    const int o0 = blockIdx.x * 128;    // over 1024 (8 tiles)
    const int pix0 = blockIdx.y * 128;  // over 65536 (512 tiles)
    const int w = t >> 6, lane = t & 63, quad = lane >> 4, ln = lane & 15;
    const int wm = w & 1, wn = w >> 1;
    const int sw = ln & 7;

    f32x4 acc[4][4];
    for (int i = 0; i < 4; ++i)
        for (int j = 0; j < 4; ++j)
            acc[i][j] = (f32x4){0.f, 0.f, 0.f, 0.f};

    for (int kk = 0; kk < KDIM; kk += 64) {
        __syncthreads();
        const bf16* gA = AO + (size_t)pix0 * KDIM + kk;
        const bf16* gB = Wp + (size_t)o0 * KDIM + kk;
        for (int it = 0; it < 4; ++it) {
            int s = (w * 4 + it) * 64 + lane;
            int row = s >> 3;
            int c = (s & 7) ^ (row & 7);
            bf16* ldsbase = &As[(size_t)(w * 4 + it) * 64 * 8];
            async_copy16(ldsbase, gA + (size_t)row * KDIM + c * 8);
            bf16* ldsbaseB = &Bs[(size_t)(w * 4 + it) * 64 * 8];
            async_copy16(ldsbaseB, gB + (size_t)row * KDIM + c * 8);
        }
        __syncthreads();
        bf16x8 af[4][2], bb[4][2];
        for (int tm = 0; tm < 4; ++tm)
            for (int ks = 0; ks < 2; ++ks) {
                int r = 64 * wm + 16 * tm + ln;
                af[tm][ks] = *(const bf16x8*)&As[r * 64 + (((ks * 4 + quad) ^ sw) * 8)];
            }
        for (int tn = 0; tn < 4; ++tn)
            for (int ks = 0; ks < 2; ++ks) {
                int r = 64 * wn + 16 * tn + ln;
                bb[tn][ks] = *(const bf16x8*)&Bs[r * 64 + (((ks * 4 + quad) ^ sw) * 8)];
            }
        for (int tm = 0; tm < 4; ++tm)
            for (int tn = 0; tn < 4; ++tn) {
                acc[tm][tn] = __builtin_amdgcn_mfma_f32_16x16x32_bf16(af[tm][0], bb[tn][0], acc[tm][tn], 0, 0, 0);
                acc[tm][tn] = __builtin_amdgcn_mfma_f32_16x16x32_bf16(af[tm][1], bb[tn][1], acc[tm][tn], 0, 0, 0);
            }
    }

    float g = gamma[0];
    float bvx[4];
    for (int tn = 0; tn < 4; ++tn) bvx[tn] = bp[o0 + 64 * wn + 16 * tn + ln];
    int bidx = (pix0 + 64 * wm) >> 6;   // wave's 64 pix rows are one batch
    float sum = 0.f, ss = 0.f;
    for (int tm = 0; tm < 4; ++tm) {
        int hw0 = 16 * tm + 4 * quad;   // rows r=0..3 -> consecutive hw
        for (int tn = 0; tn < 4; ++tn) {
            int col = o0 + 64 * wn + 16 * tn + ln;
            size_t base = ((size_t)bidx * CH + col) * HW + hw0;
            f32x4 xr = *(const f32x4*)&x[base];
            f32x4 o;
            for (int r = 0; r < 4; ++r) {
                float v = acc[tm][tn][r] + bvx[tn];
                v = g * v + (1.0f - g) * xr[r];
                o[r] = v;
                sum += v;
                ss += v * v;
            }
            *(f32x4*)&out_ws[base] = o;   // y-layout store, 16B
        }
    }
    for (int mask = 1; mask < 64; mask <<= 1) {
        sum += __shfl_xor(sum, mask);
        ss  += __shfl_xor(ss, mask);
    }
    if (lane == 0) {
        atomicAdd(&stats[2 * bidx], sum);
        atomicAdd(&stats[2 * bidx + 1], ss);
    }
}

// ---------------- LayerNorm finalize (FROZEN) ----------------
__global__ void ln_kernel(const float* __restrict__ out_ws, const float* __restrict__ stats,
                          const float* __restrict__ lnw, const float* __restrict__ lnb,
                          float* __restrict__ y) {
    const size_t total = (size_t)BATCH * CH * HW;
    const float invN = 1.0f / (float)(CH * HW);
    for (size_t i = ((size_t)blockIdx.x * 256 + threadIdx.x) * 4; i < total; i += (size_t)gridDim.x * 1024) {
        int b = (int)(i >> 16);
        int rem = (int)(i & 65535);
        float mean = stats[2 * b] * invN;
        float var = stats[2 * b + 1] * invN - mean * mean;
        float rstd = rsqrtf(var + LN_EPS);
        f32x4 v = *(const f32x4*)&out_ws[i];
        f32x4 wv = *(const f32x4*)&lnw[rem];
        f32x4 bv4 = *(const f32x4*)&lnb[rem];
        f32x4 o;
        for (int j = 0; j < 4; ++j) o[j] = (v[j] - mean) * rstd * wv[j] + bv4[j];
        *(f32x4*)&y[i] = o;
    }
}

// ---------------- launch ----------------
extern "C" void kernel_launch(void* const* d_in, const int* in_sizes, int n_in,
                              void* d_out, int out_size, void* d_ws, size_t ws_size,
                              hipStream_t stream) {
    const float* x     = (const float*)d_in[0];
    const float* Wq    = (const float*)d_in[1];
    const float* bq    = (const float*)d_in[2];
    const float* Wk    = (const float*)d_in[3];
    const float* bk    = (const float*)d_in[4];
    const float* Wv    = (const float*)d_in[5];
    const float* bv    = (const float*)d_in[6];
    const float* Wp    = (const float*)d_in[7];
    const float* bp    = (const float*)d_in[8];
    const float* gamma = (const float*)d_in[9];
    const float* temp  = (const float*)d_in[10];
    const float* lnw   = (const float*)d_in[11];
    const float* lnb   = (const float*)d_in[12];
    float* y = (float*)d_out;

    char* ws = (char*)d_ws;
    // workspace layout (bytes)
    const size_t off_wqkv = 0;                               // 3072*1024*2 = 6291456
    const size_t off_wp   = 6291456;                         // 1024*1024*2 = 2097152
    const size_t off_bias = off_wp + 2097152;                // 3072*4 = 12288
    const size_t off_stat = off_bias + 12288;                // 1024*2*4 = 8192
    const size_t off_xT   = off_stat + 8192;                 // 65536*1024*2 = 134217728
    const size_t off_qkv  = off_xT + 134217728;              // 65536*3072*2 = 402653184
    const size_t off_ao   = off_qkv + 402653184;             // 65536*1024*2 = 134217728
    const size_t off_out  = off_qkv;                         // alias: qkv dead after attention

    bf16*  wqkv_b = (bf16*)(ws + off_wqkv);
    bf16*  wp_b   = (bf16*)(ws + off_wp);
    float* bias_q = (float*)(ws + off_bias);
    float* stats  = (float*)(ws + off_stat);
    bf16*  xT     = (bf16*)(ws + off_xT);
    bf16*  qkv    = (bf16*)(ws + off_qkv);
    bf16*  ao     = (bf16*)(ws + off_ao);
    float* out_ws = (float*)(ws + off_out);

    cvt_all<<<4096, 256, 0, stream>>>(Wq, Wk, Wv, Wp, wqkv_b, wp_b);
    pack_bias<<<12, 256, 0, stream>>>(bq, bk, bv, bias_q);
    transpose_x<<<dim3(32, 1024), 256, 0, stream>>>(x, xT);
    gemm_qkv<<<dim3(3072), 512, 0, stream>>>(xT, wqkv_b, bias_q, qkv);
    attn_kernel<<<dim3(16, 1024), 256, 0, stream>>>(qkv, ao, temp);
    hipMemsetAsync(stats, 0, 8192, stream);
    gemm_proj<<<dim3(8, 512), 256, 0, stream>>>(ao, wp_b, bp, x, gamma, out_ws, stats);
    ln_kernel<<<16384, 256, 0, stream>>>(out_ws, stats, lnw, lnb, y);
}